// Round 7
// baseline (172.249 us; speedup 1.0000x reference)
//
#include <hip/hip_runtime.h>
#include <math.h>

#define B_SZ 32
#define L_SZ 32768
#define T_SZ 1024
#define PS_SZ 32
#define D_SZ 256
#define SM_M2 14.4269504f  // static softmax shift in log2 domain: 10*log2(e)

typedef float f32x4 __attribute__((ext_vector_type(4)));
typedef float f32x16 __attribute__((ext_vector_type(16)));
typedef short s16x8 __attribute__((ext_vector_type(8)));
typedef unsigned short u16x8 __attribute__((ext_vector_type(8)));
typedef unsigned int u32;
typedef unsigned int u32x2 __attribute__((ext_vector_type(2)));
typedef unsigned int u32x4 __attribute__((ext_vector_type(4)));

__device__ __forceinline__ unsigned short f2bf(float f) {
  union { float f; unsigned int u; } v; v.f = f;
  unsigned int r = v.u + 0x7FFFu + ((v.u >> 16) & 1u);
  return (unsigned short)(r >> 16);
}

__device__ __forceinline__ void g2l16(const unsigned short* g, unsigned short* l) {
  __builtin_amdgcn_global_load_lds(
      (const __attribute__((address_space(1))) unsigned int*)g,
      (__attribute__((address_space(3))) unsigned int*)l, 16, 0, 0);
}

// ---------------- prep: stats partials + weight folds + counter zero ----------------
__global__ __launch_bounds__(256) void prep_kernel(const float* __restrict__ x,
                                                   float* __restrict__ sgpart,
                                                   const float* __restrict__ Wp,
                                                   const float* __restrict__ bp,
                                                   const float* __restrict__ Wq,
                                                   const float* __restrict__ bq,
                                                   const float* __restrict__ Wo,
                                                   const float* __restrict__ bo,
                                                   const float* __restrict__ Wh,
                                                   const float* __restrict__ bh,
                                                   float* __restrict__ Wcb,
                                                   unsigned short* __restrict__ WqT,
                                                   unsigned short* __restrict__ WfT,
                                                   float* __restrict__ bfp,
                                                   unsigned int* __restrict__ total,
                                                   float* __restrict__ lsum) {
  __shared__ float red[8];
  const int g = blockIdx.x, tid = threadIdx.x;
  const int w = tid >> 6, lane = tid & 63;
  if (g < 256) {
    const int b = g >> 3;
    const float* p = x + (size_t)b * L_SZ + (size_t)(g & 7) * 4096;
    float s = 0.f, ss = 0.f;
#pragma unroll
    for (int i = 0; i < 4; ++i) {
      float4 f = ((const float4*)p)[tid + i * 256];
      s += f.x + f.y + f.z + f.w;
      ss += f.x * f.x + f.y * f.y + f.z * f.z + f.w * f.w;
    }
#pragma unroll
    for (int off = 32; off >= 1; off >>= 1) {
      s += __shfl_down(s, off);
      ss += __shfl_down(ss, off);
    }
    if (lane == 0) { red[w] = s; red[4 + w] = ss; }
    __syncthreads();
    if (tid == 0) {
      sgpart[g * 2]     = red[0] + red[1] + red[2] + red[3];
      sgpart[g * 2 + 1] = red[4] + red[5] + red[6] + red[7];
    }
  } else if (g < 388) {
    int idx = (g - 256) * 256 + tid;
    if (idx < 33 * 768) {
      int p = idx / 768, j = idx % 768;
      const float* arow = (p < 32) ? (Wp + p * 256) : bp;
      float acc = (p < 32) ? 0.f : bq[j];
      for (int d = 0; d < 256; ++d) acc += arow[d] * Wq[d * 768 + j];
      if (p < 32) WqT[j * 32 + p] = f2bf(acc);
      else Wcb[j] = acc;
    } else {
      int k = idx - 33 * 768;
      if (k < 8192) {
        int p = k >> 8, d = k & 255;
        float acc = 0.f;
        for (int e = 0; e < 256; ++e) acc += Wo[d * 256 + e] * Wh[e * 32 + p];
        WfT[p * 256 + d] = f2bf(acc);
      } else if (k < 8224) {
        int p = k - 8192;
        float acc = bh[p];
        for (int e = 0; e < 256; ++e) acc += bo[e] * Wh[e * 32 + p];
        bfp[p] = acc;
      }
    }
  } else {
    if (tid == 0) { total[0] = 0u; lsum[0] = 0.f; }
  }
}

// ---------------- qkv MFMA GEMM (verified R7/R9); V kt-tiled transposed ----------------
// Q pre-scaled by (1/16)*log2(e) so attention softmax uses raw exp2 (v_exp_f32).
__global__ __launch_bounds__(256) void qkv_kernel(const float* __restrict__ x,
                                                  const float* __restrict__ sgpart,
                                                  const unsigned short* __restrict__ WqT,
                                                  const float* __restrict__ Wcb,
                                                  unsigned short* __restrict__ Qb,
                                                  unsigned short* __restrict__ Kb,
                                                  unsigned short* __restrict__ Vtt) {
  __shared__ unsigned short T4[4][8448];
  const int tid = threadIdx.x;
  const int w = tid >> 6, lane = tid & 63;
  const int lo = lane & 15, quad = lane >> 4;
  unsigned short* Tw = T4[w];
  const int mbase = blockIdx.x * 128 + w * 32;
  const int b = mbase >> 10;
  float S = 0.f, SS = 0.f;
#pragma unroll
  for (int i = 0; i < 8; ++i) {
    S += sgpart[(b * 8 + i) * 2];
    SS += sgpart[(b * 8 + i) * 2 + 1];
  }
  const float mean = S * (1.f / (float)L_SZ);
  const float var = (SS - S * mean) * (1.f / (float)(L_SZ - 1));
  const float inv = 1.f / (sqrtf(var) + 1e-5f);
  s16x8 af0, af1;
  {
    float4 a = *(const float4*)&x[(size_t)(mbase + lo) * 32 + quad * 8];
    float4 c = *(const float4*)&x[(size_t)(mbase + lo) * 32 + quad * 8 + 4];
    af0[0] = (short)f2bf((a.x - mean) * inv); af0[1] = (short)f2bf((a.y - mean) * inv);
    af0[2] = (short)f2bf((a.z - mean) * inv); af0[3] = (short)f2bf((a.w - mean) * inv);
    af0[4] = (short)f2bf((c.x - mean) * inv); af0[5] = (short)f2bf((c.y - mean) * inv);
    af0[6] = (short)f2bf((c.z - mean) * inv); af0[7] = (short)f2bf((c.w - mean) * inv);
    float4 d = *(const float4*)&x[(size_t)(mbase + 16 + lo) * 32 + quad * 8];
    float4 e = *(const float4*)&x[(size_t)(mbase + 16 + lo) * 32 + quad * 8 + 4];
    af1[0] = (short)f2bf((d.x - mean) * inv); af1[1] = (short)f2bf((d.y - mean) * inv);
    af1[2] = (short)f2bf((d.z - mean) * inv); af1[3] = (short)f2bf((d.w - mean) * inv);
    af1[4] = (short)f2bf((e.x - mean) * inv); af1[5] = (short)f2bf((e.y - mean) * inv);
    af1[6] = (short)f2bf((e.z - mean) * inv); af1[7] = (short)f2bf((e.w - mean) * inv);
  }
  // Q (pre-scaled 1/16 * log2e)
#pragma unroll 4
  for (int nt = 0; nt < 16; ++nt) {
    s16x8 bf = *(const s16x8*)&WqT[(size_t)(nt * 16 + lo) * 32 + quad * 8];
    f32x4 c0 = {0.f, 0.f, 0.f, 0.f}, c1 = {0.f, 0.f, 0.f, 0.f};
    c0 = __builtin_amdgcn_mfma_f32_16x16x32_bf16(af0, bf, c0, 0, 0, 0);
    c1 = __builtin_amdgcn_mfma_f32_16x16x32_bf16(af1, bf, c1, 0, 0, 0);
    const int col = nt * 16 + lo;
    const float bi = Wcb[col];
#pragma unroll
    for (int i = 0; i < 4; ++i) {
      Tw[(quad * 4 + i) * 264 + col]      = f2bf((c0[i] + bi) * 0.09016844f);
      Tw[(16 + quad * 4 + i) * 264 + col] = f2bf((c1[i] + bi) * 0.09016844f);
    }
  }
#pragma unroll
  for (int it = 0; it < 16; ++it) {
    const int gsub = it * 64 + lane;
    const int row = gsub >> 5, c16 = gsub & 31;
    *(u16x8*)&Qb[(size_t)(mbase + row) * 256 + c16 * 8] =
        *(const u16x8*)&Tw[row * 264 + c16 * 8];
  }
  // K
#pragma unroll 4
  for (int nt = 0; nt < 16; ++nt) {
    s16x8 bf = *(const s16x8*)&WqT[(size_t)(256 + nt * 16 + lo) * 32 + quad * 8];
    f32x4 c0 = {0.f, 0.f, 0.f, 0.f}, c1 = {0.f, 0.f, 0.f, 0.f};
    c0 = __builtin_amdgcn_mfma_f32_16x16x32_bf16(af0, bf, c0, 0, 0, 0);
    c1 = __builtin_amdgcn_mfma_f32_16x16x32_bf16(af1, bf, c1, 0, 0, 0);
    const int col = nt * 16 + lo;
    const float bi = Wcb[256 + col];
#pragma unroll
    for (int i = 0; i < 4; ++i) {
      Tw[(quad * 4 + i) * 264 + col]      = f2bf(c0[i] + bi);
      Tw[(16 + quad * 4 + i) * 264 + col] = f2bf(c1[i] + bi);
    }
  }
#pragma unroll
  for (int it = 0; it < 16; ++it) {
    const int gsub = it * 64 + lane;
    const int row = gsub >> 5, c16 = gsub & 31;
    *(u16x8*)&Kb[(size_t)(mbase + row) * 256 + c16 * 8] =
        *(const u16x8*)&Tw[row * 264 + c16 * 8];
  }
  // V transposed, kt-tiled: Vtt[(b*32+ktq)*8192 + d*32 + t_local]
#pragma unroll 4
  for (int nt2 = 0; nt2 < 16; ++nt2) {
    s16x8 aw = *(const s16x8*)&WqT[(size_t)(512 + nt2 * 16 + lo) * 32 + quad * 8];
    f32x4 c0 = {0.f, 0.f, 0.f, 0.f}, c1 = {0.f, 0.f, 0.f, 0.f};
    c0 = __builtin_amdgcn_mfma_f32_16x16x32_bf16(aw, af0, c0, 0, 0, 0);
    c1 = __builtin_amdgcn_mfma_f32_16x16x32_bf16(aw, af1, c1, 0, 0, 0);
#pragma unroll
    for (int i = 0; i < 4; ++i) {
      const int d = nt2 * 16 + quad * 4 + i;
      const float bv = Wcb[512 + d];
      Tw[d * 32 + lo]      = f2bf(c0[i] + bv);
      Tw[d * 32 + 16 + lo] = f2bf(c1[i] + bv);
    }
  }
  {
    const int ktq = (mbase >> 5) & 31;
    const size_t vb = ((size_t)b * 32 + ktq) * 8192;
#pragma unroll
    for (int it = 0; it < 16; ++it) {
      const int gsub = it * 64 + lane;
      *(u16x8*)&Vtt[vb + gsub * 8] = *(const u16x8*)&Tw[gsub * 8];
    }
  }
}

// ------ flash attention: depth-3 ring + FIXED producers with pinned-resident Q ------
// 256 blocks x 512 thr (8 waves), 1 block/CU, ring 4x32KB, counted vmcnt (R5 ✓),
// P-exchange via LDS (R6 ✓). Change vs R6: producers are FIXED (w=0 tile0/SIMD0,
// w=5 tile1/SIMD1) instead of rotating. R6's rotation forced all 8 waves to keep
// qf[16] (64 VGPR) live-but-rarely-used; at VGPR_Count=104 the compiler REMATERIALIZED
// qf via global reloads inside every PRODUCE (~16 L2/L3 loads on the critical path
// per step = the ~4k cyc/step gap). Now only producer waves load qf, use it every
// step, and each fragment is pinned with asm "+v" (opaque value -> remat impossible,
// must stay in registers; budget 256 at 2 waves/SIMD). Softmax uses raw exp2f
// (Q pre-scaled by log2e in qkv) -- v_exp_f32 is natively 2^x.
__global__ __launch_bounds__(512, 2) void attn_kernel(const unsigned short* __restrict__ Qb,
                                                      const unsigned short* __restrict__ Kb,
                                                      const unsigned short* __restrict__ Vtt,
                                                      const unsigned short* __restrict__ WfT,
                                                      const float* __restrict__ bfp,
                                                      const float* __restrict__ x,
                                                      const float* __restrict__ sgpart,
                                                      float* __restrict__ lsum,
                                                      unsigned int* __restrict__ total,
                                                      float* __restrict__ out) {
  __shared__ unsigned short SMEM[65536];      // 4 ring slots x 16384 shorts
  __shared__ unsigned short Pbuf[2][2][1280]; // [tile][slot][32 rows x 40 shorts]
  __shared__ float OlL[2][32];
  __shared__ float redf[8];
  const int g = blockIdx.x;
  const int b = (g & 7) * 4 + ((g >> 3) & 3);  // XCD (g%8) pinned: 4 batches per XCD
  const int p = g >> 5;                        // 0..7 -> groups p and 15-p
  const int tid = threadIdx.x;
  const int w = tid >> 6, lane = tid & 63;
  const int th = w >> 2, dq = w & 3;           // tile-in-group, dim quarter
  const int cl = lane & 31, hi = lane >> 5;
  const bool isprod = (w == 0) || (w == 5);    // fixed producers, SIMD 0 and SIMD 1

  const unsigned short* KbB = Kb + (size_t)b * 262144;
  const unsigned short* VtB = Vtt + (size_t)b * 262144;
  unsigned short* QbM = (unsigned short*)Qb;

  // staging addresses (R5-verified, 0 conflicts): source inverse-swizzled, dest linear
  const int c0 = tid, c1 = 512 + tid;
  const int ks0 = (c0 >> 5) * 256 + (((c0 & 31) ^ (c0 >> 5)) * 8);
  const int ks1 = (c1 >> 5) * 256 + (((c1 & 31) ^ (c1 >> 5)) * 8);
  const int vs0 = (c0 >> 2) * 32 + (((c0 & 3) ^ ((c0 >> 4) & 3)) * 8);
  const int vs1 = (c1 >> 2) * 32 + (((c1 & 3) ^ ((c1 >> 4) & 3)) * 8);
  const int kd0 = w * 512, kd1 = 4096 + w * 512;

  auto STAGE = [&](int t) {
    const unsigned short* kg = KbB + (size_t)t * 8192;
    const unsigned short* vg = VtB + (size_t)t * 8192;
    unsigned short* Lb = &SMEM[(t & 3) * 16384];
    g2l16(kg + ks0, Lb + kd0);
    g2l16(kg + ks1, Lb + kd1);
    g2l16(vg + vs0, Lb + 8192 + kd0);
    g2l16(vg + vs1, Lb + 8192 + kd1);
  };

  s16x8 qf[16];
  f32x16 O0, O1;
  float Ol = 0.f;
  const int vsz = (cl >> 2) & 3;
  const int cva = (hi ^ vsz) * 8, cvb = ((2 | hi) ^ vsz) * 8;

  // producer: QK^T(sp) -> softmax (exp2) -> pack -> P[th][sp&1]
  auto PRODUCE = [&](int sp, int myti_) {
    const unsigned short* Lk = &SMEM[(sp & 3) * 16384];
    f32x16 Sx;
#pragma unroll
    for (int i = 0; i < 16; ++i) Sx[i] = 0.f;
#pragma unroll
    for (int cb = 0; cb < 16; ++cb) {
      const int ch = (2 * cb + hi) ^ cl;
      s16x8 kf = *(const s16x8*)&Lk[cl * 256 + ch * 8];
      Sx = __builtin_amdgcn_mfma_f32_32x32x16_bf16(kf, qf[cb], Sx, 0, 0, 0);
    }
    const bool diag = (sp == myti_);
    unsigned short* Pd = &Pbuf[th][sp & 1][0];
#pragma unroll
    for (int gq = 0; gq < 4; ++gq) {
      float ev[4];
#pragma unroll
      for (int q2 = 0; q2 < 4; ++q2) {
        const int r = gq * 4 + q2;
        const int trow = q2 + 8 * gq + 4 * hi;
        float e = exp2f(Sx[r] - SM_M2);
        if (diag && trow > cl) e = 0.f;
        ev[q2] = e;
        Ol += e;
      }
      u32x2 pr;
      pr[0] = (u32)f2bf(ev[0]) | ((u32)f2bf(ev[1]) << 16);
      pr[1] = (u32)f2bf(ev[2]) | ((u32)f2bf(ev[3]) << 16);
      *(u32x2*)&Pd[cl * 40 + (2 * gq + hi) * 4] = pr;
    }
  };

  auto run_phase = [&](int gph) {
    const int nk = 2 * gph + 2;
    const int myti = 2 * gph + th;
    if (isprod) {
      const size_t qrow = ((size_t)b * 1024 + myti * 32 + cl) * 256;
#pragma unroll
      for (int cb = 0; cb < 16; ++cb) {
        qf[cb] = *(const s16x8*)&Qb[qrow + cb * 16 + hi * 8];
        asm volatile("" : "+v"(qf[cb]));  // pin: opaque value, remat impossible
      }
    }
#pragma unroll
    for (int i = 0; i < 16; ++i) { O0[i] = 0.f; O1[i] = 0.f; }
    Ol = 0.f;
    if (nk >= 3) {
      STAGE(0); STAGE(1); STAGE(2);
      asm volatile("s_waitcnt vmcnt(8)" ::: "memory");  // slot0 landed
    } else {
      STAGE(0); STAGE(1);
      asm volatile("s_waitcnt vmcnt(4)" ::: "memory");
    }
    __builtin_amdgcn_s_barrier();                       // everyone's slot-0 visible
    if (isprod) PRODUCE(0, myti);
    for (int s = 0; s < nk; ++s) {
      asm volatile("s_waitcnt lgkmcnt(0)" ::: "memory");  // P-writes visible pre-barrier
      if (s + 2 < nk) asm volatile("s_waitcnt vmcnt(4)" ::: "memory");  // slot s+1 ready
      else            asm volatile("s_waitcnt vmcnt(0)" ::: "memory");
      __builtin_amdgcn_s_barrier();
      __builtin_amdgcn_sched_barrier(0);
      if (s + 3 < nk) STAGE(s + 3);
      if (s + 1 <= myti && isprod) PRODUCE(s + 1, myti);
      if (s <= myti) {  // PV(s): P from LDS + V from ring slot s
        const unsigned short* Pp = &Pbuf[th][s & 1][0];
        s16x8 pa = *(const s16x8*)&Pp[cl * 40 + 8 * hi];
        s16x8 pb = *(const s16x8*)&Pp[cl * 40 + 16 + 8 * hi];
        const unsigned short* Lv = &SMEM[(s & 3) * 16384 + 8192];
        const int d0 = (dq * 64 + cl) * 32;
        s16x8 v0 = *(const s16x8*)&Lv[d0 + cva];
        s16x8 v1 = *(const s16x8*)&Lv[d0 + cvb];
        O0 = __builtin_amdgcn_mfma_f32_32x32x16_bf16(pa, v0, O0, 0, 0, 0);
        O0 = __builtin_amdgcn_mfma_f32_32x32x16_bf16(pb, v1, O0, 0, 0, 0);
        s16x8 v2 = *(const s16x8*)&Lv[d0 + 1024 + cva];
        s16x8 v3 = *(const s16x8*)&Lv[d0 + 1024 + cvb];
        O1 = __builtin_amdgcn_mfma_f32_32x32x16_bf16(pa, v2, O1, 0, 0, 0);
        O1 = __builtin_amdgcn_mfma_f32_32x32x16_bf16(pb, v3, O1, 0, 0, 0);
      }
    }
    Ol += __shfl_xor(Ol, 32);  // producer holds full denominator for q = cl
  };

  // ---- phase A: group p; park normalized O in this block's (dead) Qb rows ----
  run_phase(p);
  if (isprod && hi == 0) OlL[th][cl] = Ol;
  __syncthreads();
  {
    const float dsum = OlL[th][cl];
    const size_t obase = ((size_t)b * 1024 + (2 * p + th) * 32) * 256;
#pragma unroll
    for (int r = 0; r < 16; ++r) {
      const int row = (r & 3) + 8 * (r >> 2) + 4 * hi;
      const float iv = 1.f / __shfl(dsum, row);
      QbM[obase + row * 256 + dq * 64 + cl]      = f2bf(O0[r] * iv);
      QbM[obase + row * 256 + dq * 64 + 32 + cl] = f2bf(O1[r] * iv);
    }
  }
  __syncthreads();  // OlL reuse + ring reuse guard before phase B

  // ---- phase B: group 15-p ----
  run_phase(15 - p);
  if (isprod && hi == 0) OlL[th][cl] = Ol;
  __syncthreads();
  unsigned short* OLs = SMEM;  // overlay: 64 x 264 bf16 (rows th*32+row)
  {
    const float dsum = OlL[th][cl];
#pragma unroll
    for (int r = 0; r < 16; ++r) {
      const int row = (r & 3) + 8 * (r >> 2) + 4 * hi;
      const float iv = 1.f / __shfl(dsum, row);
      OLs[(th * 32 + row) * 264 + dq * 64 + cl]      = f2bf(O0[r] * iv);
      OLs[(th * 32 + row) * 264 + dq * 64 + 32 + cl] = f2bf(O1[r] * iv);
    }
  }
  __syncthreads();

  // ---- epilogue: 4 head GEMMs (waves 0..3, one 32-row tile each) + fused MSE ----
  float lacc = 0.f;
  if (w < 4) {
    const int tile = (w == 0) ? 2 * p : (w == 1) ? 2 * p + 1
                   : (w == 2) ? 30 - 2 * p : 31 - 2 * p;
    s16x8 af[16];
    if (w < 2) {
      const size_t abase = ((size_t)b * 1024 + tile * 32 + cl) * 256;
#pragma unroll
      for (int cb = 0; cb < 16; ++cb)
        af[cb] = *(const s16x8*)&QbM[abase + cb * 16 + hi * 8];
    } else {
      const int sub = w - 2;
#pragma unroll
      for (int cb = 0; cb < 16; ++cb)
        af[cb] = *(const s16x8*)&OLs[(sub * 32 + cl) * 264 + cb * 16 + hi * 8];
    }
    f32x16 hacc;
#pragma unroll
    for (int i = 0; i < 16; ++i) hacc[i] = 0.f;
#pragma unroll
    for (int cb = 0; cb < 16; ++cb) {
      s16x8 bfr = *(const s16x8*)&WfT[(size_t)cl * 256 + cb * 16 + hi * 8];
      hacc = __builtin_amdgcn_mfma_f32_32x32x16_bf16(af[cb], bfr, hacc, 0, 0, 0);
    }
    float S_ = 0.f, SS = 0.f;
#pragma unroll
    for (int i = 0; i < 8; ++i) {
      S_ += sgpart[(b * 8 + i) * 2];
      SS += sgpart[(b * 8 + i) * 2 + 1];
    }
    const float mean = S_ * (1.f / (float)L_SZ);
    const float var = (SS - S_ * mean) * (1.f / (float)(L_SZ - 1));
    const float invb = 1.f / (sqrtf(var) + 1e-5f);
    const float ba = bfp[cl];
#pragma unroll
    for (int r = 0; r < 16; ++r) {
      const int row = (r & 3) + 8 * (r >> 2) + 4 * hi;
      const int t = tile * 32 + row;
      if (t < 1023) {
        const float pr = hacc[r] + ba;
        const float tg = (x[(size_t)b * L_SZ + (t + 1) * 32 + cl] - mean) * invb;
        const float d = pr - tg;
        lacc += d * d;
      }
    }
#pragma unroll
    for (int off = 32; off >= 1; off >>= 1) lacc += __shfl_down(lacc, off);
  }
  if (lane == 0) redf[w] = lacc;
  __syncthreads();

  // ---- in-kernel loss finalize (device-scope counter pattern, verified R10) ----
  if (tid == 0) {
    atomicAdd(lsum, redf[0] + redf[1] + redf[2] + redf[3]);
    __threadfence();
    unsigned int prev = atomicAdd(total, 1u);
    if (prev == 255u) {
      float tot = atomicAdd(lsum, 0.0f);  // device-scope read including all adds
      out[0] = tot * (1.f / (float)(B_SZ * (T_SZ - 1) * PS_SZ));
    }
  }
}

extern "C" void kernel_launch(void* const* d_in, const int* in_sizes, int n_in,
                              void* d_out, int out_size, void* d_ws, size_t ws_size,
                              hipStream_t stream) {
  const float* x      = (const float*)d_in[0];
  const float* W_proj = (const float*)d_in[1];
  const float* b_proj = (const float*)d_in[2];
  const float* W_qkv  = (const float*)d_in[3];
  const float* b_qkv  = (const float*)d_in[4];
  const float* W_out  = (const float*)d_in[5];
  const float* b_out  = (const float*)d_in[6];
  const float* W_head = (const float*)d_in[7];
  const float* b_head = (const float*)d_in[8];
  float* out = (float*)d_out;
  char* ws = (char*)d_ws;

  unsigned short* Qb     = (unsigned short*)ws;
  unsigned short* Kb     = (unsigned short*)(ws + (16ull << 20));
  unsigned short* Vtt    = (unsigned short*)(ws + (32ull << 20));
  char* tail = ws + (48ull << 20);
  float*          Wcb    = (float*)tail;                        // 768 fp32 folded qkv bias
  unsigned short* WqT    = (unsigned short*)(tail + 4096);      // 768x32 bf16
  unsigned short* WfT    = (unsigned short*)(tail + 65536);     // 32x256 bf16
  float*          bfp    = (float*)(tail + 98304);              // 32 fp32
  float*          sgpart = (float*)(tail + 102400);             // 256x2 fp32
  unsigned int*   total  = (unsigned int*)(tail + 106496);      // 1 ctr
  float*          lsum   = (float*)(tail + 106496 + 64);        // 1 fp32

  prep_kernel<<<389, 256, 0, stream>>>(x, sgpart, W_proj, b_proj, W_qkv, b_qkv,
                                       W_out, b_out, W_head, b_head,
                                       Wcb, WqT, WfT, bfp, total, lsum);
  qkv_kernel<<<256, 256, 0, stream>>>(x, sgpart, WqT, Wcb, Qb, Kb, Vtt);
  attn_kernel<<<256, 512, 0, stream>>>(Qb, Kb, Vtt, WfT, bfp, x, sgpart, lsum, total, out);
}